// Round 1
// baseline (874.577 us; speedup 1.0000x reference)
//
#include <hip/hip_runtime.h>
#include <stdint.h>

// Problem constants: B=16, S=1024, D=512, H=8, HD=64
typedef unsigned short u16;
typedef __attribute__((ext_vector_type(8))) __bf16 bf16x8;
typedef __attribute__((ext_vector_type(4))) float f32x4;

__device__ __forceinline__ u16 f2bf(float f) {
    unsigned u = __float_as_uint(f);
    u += 0x7fffu + ((u >> 16) & 1u);
    return (u16)(u >> 16);
}
__device__ __forceinline__ float bf2f(u16 h) {
    return __uint_as_float(((unsigned)h) << 16);
}

// ---------------- K0: convert Q -> bf16, W{q,k,v} -> bf16, row-valid mask ----
__global__ void k_prep(const float* __restrict__ Q,
                       const float* __restrict__ Wq, const float* __restrict__ Wk,
                       const float* __restrict__ Wv,
                       u16* __restrict__ qb, u16* __restrict__ wall,
                       float* __restrict__ fmask) {
    int bid = blockIdx.x;
    int t = threadIdx.x;  // 64 threads = 1 wave
    if (bid < 16384) {
        const float* src = Q + (size_t)bid * 512;
        u16* dst = qb + (size_t)bid * 512;
        float4 v0 = *(const float4*)(src + t * 4);
        float4 v1 = *(const float4*)(src + 256 + t * 4);
        bool nz = (v0.x != 0.f) || (v0.y != 0.f) || (v0.z != 0.f) || (v0.w != 0.f) ||
                  (v1.x != 0.f) || (v1.y != 0.f) || (v1.z != 0.f) || (v1.w != 0.f);
        ushort4 o0 = make_ushort4(f2bf(v0.x), f2bf(v0.y), f2bf(v0.z), f2bf(v0.w));
        ushort4 o1 = make_ushort4(f2bf(v1.x), f2bf(v1.y), f2bf(v1.z), f2bf(v1.w));
        *(ushort4*)(dst + t * 4) = o0;
        *(ushort4*)(dst + 256 + t * 4) = o1;
        unsigned long long bal = __ballot(nz);
        if (t == 0) fmask[bid] = bal ? 0.0f : -1e30f;
    } else {
        int r = bid - 16384;  // 0..1535
        const float* W = (r < 512) ? Wq : (r < 1024) ? Wk : Wv;
        const float* src = W + (size_t)(r & 511) * 512;
        u16* dst = wall + (size_t)r * 512;
        float4 v0 = *(const float4*)(src + t * 4);
        float4 v1 = *(const float4*)(src + 256 + t * 4);
        ushort4 o0 = make_ushort4(f2bf(v0.x), f2bf(v0.y), f2bf(v0.z), f2bf(v0.w));
        ushort4 o1 = make_ushort4(f2bf(v1.x), f2bf(v1.y), f2bf(v1.z), f2bf(v1.w));
        *(ushort4*)(dst + t * 4) = o0;
        *(ushort4*)(dst + 256 + t * 4) = o1;
    }
}

// ---------------- K1: fused QKV projection GEMM (BT form) -------------------
// C[m,n] = relu(sum_k qb[m,k]*wall[n,k] + bias[n]), M=16384, N=1536, K=512
// 128x128 tile, BK=32, 4 waves each computing a 64x64 quadrant (4x4 frags).
__global__ __launch_bounds__(256) void k_qkv(
        const u16* __restrict__ qb, const u16* __restrict__ wall,
        const float* __restrict__ bq, const float* __restrict__ bk,
        const float* __restrict__ bv,
        u16* __restrict__ oq, u16* __restrict__ ok, u16* __restrict__ ov) {
    __shared__ u16 As[128 * 32];
    __shared__ u16 Bs[128 * 32];
    int bm = blockIdx.x, bn = blockIdx.y;
    int tid = threadIdx.x, lane = tid & 63, wid = tid >> 6;
    int wm = wid >> 1, wn = wid & 1;
    int q4 = lane >> 4, l16 = lane & 15;

    f32x4 acc[4][4];
#pragma unroll
    for (int i = 0; i < 4; ++i)
#pragma unroll
        for (int j = 0; j < 4; ++j) acc[i][j] = (f32x4){0.f, 0.f, 0.f, 0.f};

#pragma unroll 1
    for (int kk = 0; kk < 16; ++kk) {
        float4 av[2], bw[2];
#pragma unroll
        for (int c = 0; c < 2; ++c) {
            int id = c * 256 + tid;
            int r = id >> 2, cb = (id & 3) * 8;
            av[c] = *(const float4*)(qb + ((size_t)(bm * 128 + r)) * 512 + kk * 32 + cb);
            bw[c] = *(const float4*)(wall + ((size_t)(bn * 128 + r)) * 512 + kk * 32 + cb);
        }
        __syncthreads();
#pragma unroll
        for (int c = 0; c < 2; ++c) {
            int id = c * 256 + tid;
            int r = id >> 2, cb = (id & 3) * 8;
            *(float4*)(&As[r * 32 + cb]) = av[c];
            *(float4*)(&Bs[r * 32 + cb]) = bw[c];
        }
        __syncthreads();
        bf16x8 af[4], bf[4];
#pragma unroll
        for (int i = 0; i < 4; ++i)
            af[i] = *(const bf16x8*)(&As[(wm * 64 + i * 16 + l16) * 32 + q4 * 8]);
#pragma unroll
        for (int j = 0; j < 4; ++j)
            bf[j] = *(const bf16x8*)(&Bs[(wn * 64 + j * 16 + l16) * 32 + q4 * 8]);
#pragma unroll
        for (int i = 0; i < 4; ++i)
#pragma unroll
            for (int j = 0; j < 4; ++j)
                acc[i][j] = __builtin_amdgcn_mfma_f32_16x16x32_bf16(af[i], bf[j], acc[i][j], 0, 0, 0);
    }

    int which = bn >> 2;  // 0=q 1=k 2=v (128-col block stays within one 512 group)
    const float* bias = (which == 0) ? bq : (which == 1) ? bk : bv;
    u16* outp = (which == 0) ? oq : (which == 1) ? ok : ov;
#pragma unroll
    for (int i = 0; i < 4; ++i)
#pragma unroll
        for (int j = 0; j < 4; ++j) {
            int n = bn * 128 + wn * 64 + j * 16 + l16;
            int c = n & 511;
            float bb = bias[c];
#pragma unroll
            for (int r = 0; r < 4; ++r) {
                int m = bm * 128 + wm * 64 + i * 16 + q4 * 4 + r;
                float val = acc[i][j][r] + bb;
                val = fmaxf(val, 0.f);
                outp[(size_t)m * 512 + c] = f2bf(val);
            }
        }
}

// ---------------- K1b: transpose V [16384][512] -> vT [8192][1024] ----------
// vT[(b*512 + c)][s] = v[b*1024 + s][c]
__global__ void k_vt(const u16* __restrict__ v, u16* __restrict__ vT) {
    __shared__ u16 tile[32][33];
    int bmRow = blockIdx.x;  // 0..511 (m tiles of 32)
    int bc = blockIdx.y;     // 0..15  (c tiles of 32)
    int tx = threadIdx.x & 31, ty = threadIdx.x >> 5;  // ty 0..7
#pragma unroll
    for (int q = 0; q < 4; ++q) {
        int ml = ty + q * 8;
        tile[ml][tx] = v[((size_t)(bmRow * 32 + ml)) * 512 + bc * 32 + tx];
    }
    __syncthreads();
    int b = bmRow >> 5;
    int sbase = (bmRow & 31) * 32;
#pragma unroll
    for (int q = 0; q < 4; ++q) {
        int cl = ty + q * 8;
        vT[((size_t)(b * 512 + bc * 32 + cl)) * 1024 + sbase + tx] = tile[tx][cl];
    }
}

// ---------------- K2: two-pass fused attention ------------------------------
// Block: (b, h, q-tile of 64 rows). 4 waves, each owns 16 q-rows.
// Pass1: QK^T -> running row max + sumexp.  Pass2: recompute QK^T, w=exp(s-m)/l,
// write weights (fp32 output), LDS round-trip w->A-frag, PV MFMA, +residual.
__global__ __launch_bounds__(256, 2) void k_attn(
        const u16* __restrict__ qv, const u16* __restrict__ kv,
        const u16* __restrict__ vT, const float* __restrict__ fmask,
        float* __restrict__ outAtt, float* __restrict__ outW) {
    __shared__ u16 Qs[64 * 72];        // [row][72] padded
    __shared__ u16 Ks[128 * 72];       // [key][72] padded
    __shared__ u16 Vs[64 * 136];       // [hd][136] padded (transposed V tile)
    __shared__ u16 Ws[4 * 16 * 136];   // per-wave w strip [16][136]
    __shared__ float kmf[128];

    int bid = blockIdx.x;
    int qt = bid & 15, h = (bid >> 4) & 7, b = bid >> 7;
    int tid = threadIdx.x, lane = tid & 63, w = tid >> 6;
    int q4 = lane >> 4, l16 = lane & 15;
    const float scale = 0.125f;

    size_t qrow0 = (size_t)b * 1024 + qt * 64;
    size_t headcol = (size_t)h * 64;

    // stage Qs (64 rows x 64 cols)
#pragma unroll
    for (int c = 0; c < 2; ++c) {
        int id = c * 256 + tid;
        int r = id >> 3, cb = (id & 7) * 8;
        float4 t4 = *(const float4*)(qv + (qrow0 + r) * 512 + headcol + cb);
        *(float4*)(&Qs[r * 72 + cb]) = t4;
    }

    float qmv[4], mrun[4], lrun[4];
#pragma unroll
    for (int r = 0; r < 4; ++r) {
        qmv[r] = fmask[qrow0 + w * 16 + q4 * 4 + r];
        mrun[r] = -3e38f;
        lrun[r] = 0.f;
    }

    // ---------------- pass 1 ----------------
    for (int kt = 0; kt < 8; ++kt) {
        __syncthreads();
        size_t krow0 = (size_t)b * 1024 + kt * 128;
#pragma unroll
        for (int c = 0; c < 4; ++c) {
            int id = c * 256 + tid;
            int r = id >> 3, cb = (id & 7) * 8;
            float4 t4 = *(const float4*)(kv + (krow0 + r) * 512 + headcol + cb);
            *(float4*)(&Ks[r * 72 + cb]) = t4;
        }
        if (tid < 128) kmf[tid] = fmask[krow0 + tid];
        __syncthreads();

        bf16x8 a0 = *(const bf16x8*)(&Qs[(w * 16 + l16) * 72 + q4 * 8]);
        bf16x8 a1 = *(const bf16x8*)(&Qs[(w * 16 + l16) * 72 + 32 + q4 * 8]);
        float km[8];
#pragma unroll
        for (int j = 0; j < 8; ++j) km[j] = kmf[j * 16 + l16];
        f32x4 acc[8];
#pragma unroll
        for (int j = 0; j < 8; ++j) acc[j] = (f32x4){0.f, 0.f, 0.f, 0.f};
#pragma unroll
        for (int j = 0; j < 8; ++j) {
            bf16x8 b0 = *(const bf16x8*)(&Ks[(j * 16 + l16) * 72 + q4 * 8]);
            bf16x8 b1 = *(const bf16x8*)(&Ks[(j * 16 + l16) * 72 + 32 + q4 * 8]);
            acc[j] = __builtin_amdgcn_mfma_f32_16x16x32_bf16(a0, b0, acc[j], 0, 0, 0);
            acc[j] = __builtin_amdgcn_mfma_f32_16x16x32_bf16(a1, b1, acc[j], 0, 0, 0);
        }
#pragma unroll
        for (int r = 0; r < 4; ++r) {
            float mt = -3e38f;
#pragma unroll
            for (int j = 0; j < 8; ++j) {
                float s = acc[j][r] * scale + qmv[r] + km[j];
                acc[j][r] = s;
                mt = fmaxf(mt, s);
            }
#pragma unroll
            for (int mm = 1; mm <= 8; mm <<= 1) mt = fmaxf(mt, __shfl_xor(mt, mm, 64));
            float mnew = fmaxf(mrun[r], mt);
            float ps = 0.f;
#pragma unroll
            for (int j = 0; j < 8; ++j) ps += __expf(acc[j][r] - mnew);
#pragma unroll
            for (int mm = 1; mm <= 8; mm <<= 1) ps += __shfl_xor(ps, mm, 64);
            lrun[r] = lrun[r] * __expf(mrun[r] - mnew) + ps;
            mrun[r] = mnew;
        }
    }
    float rl[4];
#pragma unroll
    for (int r = 0; r < 4; ++r)
        rl[r] = (qmv[r] == 0.f) ? (1.f / lrun[r]) : 0.f;  // fully-masked row -> w=0

    // ---------------- pass 2 ----------------
    f32x4 accO[4];
#pragma unroll
    for (int jn = 0; jn < 4; ++jn) accO[jn] = (f32x4){0.f, 0.f, 0.f, 0.f};
    size_t wbase = ((size_t)(b * 8 + h)) * 1024 * 1024;
    u16* wsw = &Ws[w * 16 * 136];

    for (int kt = 0; kt < 8; ++kt) {
        __syncthreads();
        size_t krow0 = (size_t)b * 1024 + kt * 128;
#pragma unroll
        for (int c = 0; c < 4; ++c) {
            int id = c * 256 + tid;
            int r = id >> 3, cb = (id & 7) * 8;
            float4 t4 = *(const float4*)(kv + (krow0 + r) * 512 + headcol + cb);
            *(float4*)(&Ks[r * 72 + cb]) = t4;
        }
#pragma unroll
        for (int c = 0; c < 4; ++c) {
            int id = c * 256 + tid;
            int hd = id >> 4, cb = (id & 15) * 8;
            float4 t4 = *(const float4*)(vT + ((size_t)(b * 512) + headcol + hd) * 1024 + kt * 128 + cb);
            *(float4*)(&Vs[hd * 136 + cb]) = t4;
        }
        if (tid < 128) kmf[tid] = fmask[krow0 + tid];
        __syncthreads();

        bf16x8 a0 = *(const bf16x8*)(&Qs[(w * 16 + l16) * 72 + q4 * 8]);
        bf16x8 a1 = *(const bf16x8*)(&Qs[(w * 16 + l16) * 72 + 32 + q4 * 8]);
        float km[8];
#pragma unroll
        for (int j = 0; j < 8; ++j) km[j] = kmf[j * 16 + l16];
        f32x4 acc[8];
#pragma unroll
        for (int j = 0; j < 8; ++j) acc[j] = (f32x4){0.f, 0.f, 0.f, 0.f};
#pragma unroll
        for (int j = 0; j < 8; ++j) {
            bf16x8 b0 = *(const bf16x8*)(&Ks[(j * 16 + l16) * 72 + q4 * 8]);
            bf16x8 b1 = *(const bf16x8*)(&Ks[(j * 16 + l16) * 72 + 32 + q4 * 8]);
            acc[j] = __builtin_amdgcn_mfma_f32_16x16x32_bf16(a0, b0, acc[j], 0, 0, 0);
            acc[j] = __builtin_amdgcn_mfma_f32_16x16x32_bf16(a1, b1, acc[j], 0, 0, 0);
        }
#pragma unroll
        for (int j = 0; j < 8; ++j) {
#pragma unroll
            for (int r = 0; r < 4; ++r) {
                int rowC = q4 * 4 + r;
                float s = acc[j][r] * scale + qmv[r] + km[j];
                float wv = __expf(s - mrun[r]) * rl[r];
                outW[wbase + (size_t)(qt * 64 + w * 16 + rowC) * 1024 + kt * 128 + j * 16 + l16] = wv;
                wsw[rowC * 136 + j * 16 + l16] = f2bf(wv);
            }
        }
        // PV: A = w strip (wave-local LDS, compiler inserts lgkmcnt), B = Vs^T
#pragma unroll
        for (int ks = 0; ks < 4; ++ks) {
            bf16x8 aw = *(const bf16x8*)(&wsw[l16 * 136 + ks * 32 + q4 * 8]);
#pragma unroll
            for (int jn = 0; jn < 4; ++jn) {
                bf16x8 bv = *(const bf16x8*)(&Vs[(jn * 16 + l16) * 136 + ks * 32 + q4 * 8]);
                accO[jn] = __builtin_amdgcn_mfma_f32_16x16x32_bf16(aw, bv, accO[jn], 0, 0, 0);
            }
        }
    }

    // epilogue: += residual q, store fp32 to out region
#pragma unroll
    for (int jn = 0; jn < 4; ++jn)
#pragma unroll
        for (int r = 0; r < 4; ++r) {
            int rowC = q4 * 4 + r;
            int hd = jn * 16 + l16;
            float qres = bf2f(Qs[(w * 16 + rowC) * 72 + hd]);
            float o = accO[jn][r] + qres;
            outAtt[(qrow0 + w * 16 + rowC) * 512 + headcol + hd] = o;
        }
}

// ---------------- K3: in-place LayerNorm + relu over D=512 ------------------
__global__ void k_ln(float* __restrict__ io, const float* __restrict__ lw,
                     const float* __restrict__ lb) {
    int row = blockIdx.x;
    int t = threadIdx.x;  // 64 threads = 1 wave
    float* p = io + (size_t)row * 512;
    float4 x0 = *(const float4*)(p + t * 4);
    float4 x1 = *(const float4*)(p + 256 + t * 4);
    float s = x0.x + x0.y + x0.z + x0.w + x1.x + x1.y + x1.z + x1.w;
    float s2 = x0.x * x0.x + x0.y * x0.y + x0.z * x0.z + x0.w * x0.w +
               x1.x * x1.x + x1.y * x1.y + x1.z * x1.z + x1.w * x1.w;
#pragma unroll
    for (int mm = 1; mm <= 32; mm <<= 1) {
        s += __shfl_xor(s, mm, 64);
        s2 += __shfl_xor(s2, mm, 64);
    }
    float mean = s * (1.f / 512.f);
    float var = s2 * (1.f / 512.f) - mean * mean;
    float inv = rsqrtf(var + 1e-5f);
    float4 w0 = *(const float4*)(lw + t * 4);
    float4 w1 = *(const float4*)(lw + 256 + t * 4);
    float4 b0 = *(const float4*)(lb + t * 4);
    float4 b1 = *(const float4*)(lb + 256 + t * 4);
    float4 o0, o1;
    o0.x = fmaxf((x0.x - mean) * inv * w0.x + b0.x, 0.f);
    o0.y = fmaxf((x0.y - mean) * inv * w0.y + b0.y, 0.f);
    o0.z = fmaxf((x0.z - mean) * inv * w0.z + b0.z, 0.f);
    o0.w = fmaxf((x0.w - mean) * inv * w0.w + b0.w, 0.f);
    o1.x = fmaxf((x1.x - mean) * inv * w1.x + b1.x, 0.f);
    o1.y = fmaxf((x1.y - mean) * inv * w1.y + b1.y, 0.f);
    o1.z = fmaxf((x1.z - mean) * inv * w1.z + b1.z, 0.f);
    o1.w = fmaxf((x1.w - mean) * inv * w1.w + b1.w, 0.f);
    *(float4*)(p + t * 4) = o0;
    *(float4*)(p + 256 + t * 4) = o1;
}

// ---------------- launcher --------------------------------------------------
extern "C" void kernel_launch(void* const* d_in, const int* in_sizes, int n_in,
                              void* d_out, int out_size, void* d_ws, size_t ws_size,
                              hipStream_t stream) {
    const float* Q = (const float*)d_in[0];
    const float* Wq_w = (const float*)d_in[1];
    const float* Wq_b = (const float*)d_in[2];
    const float* Wk_w = (const float*)d_in[3];
    const float* Wk_b = (const float*)d_in[4];
    const float* Wv_w = (const float*)d_in[5];
    const float* Wv_b = (const float*)d_in[6];
    const float* ln_w = (const float*)d_in[7];
    const float* ln_b = (const float*)d_in[8];

    // workspace layout (u16 element offsets); total ~85.5 MB
    u16* ws16 = (u16*)d_ws;
    u16* qb   = ws16;                  // [16384][512] bf16
    u16* wall = ws16 + 8388608;        // [1536][512] bf16
    u16* oq   = ws16 + 9175040;        // [16384][512] bf16
    u16* okk  = ws16 + 17563648;       // [16384][512] bf16
    u16* ov   = ws16 + 25952256;       // [16384][512] bf16
    u16* vT   = ws16 + 34340864;       // [8192][1024] bf16
    float* fmask = (float*)((char*)d_ws + 85458944);  // [16384] f32

    float* outAtt = (float*)d_out;               // [16,1024,512]
    float* outW = (float*)d_out + 8388608;       // [128,1024,1024]

    k_prep<<<17920, 64, 0, stream>>>(Q, Wq_w, Wk_w, Wv_w, qb, wall, fmask);
    k_qkv<<<dim3(128, 12), 256, 0, stream>>>(qb, wall, Wq_b, Wk_b, Wv_b, oq, okk, ov);
    k_vt<<<dim3(512, 16), 256, 0, stream>>>(ov, vT);
    k_attn<<<2048, 256, 0, stream>>>(oq, okk, vT, fmask, outAtt, outW);
    k_ln<<<16384, 64, 0, stream>>>(outAtt, ln_w, ln_b);
}